// Round 7
// baseline (226.402 us; speedup 1.0000x reference)
//
#include <hip/hip_runtime.h>

#define SPLINE_OFF 25165824   // splines output offset (6120 floats follow)
#define STEP_F (1.0f/9.0f)
#define NBLK 256

typedef float f32x4 __attribute__((ext_vector_type(4)));

// ---------------------------------------------------------------------------
// Fused resize: jax.image.resize bilinear antialias, 1024 -> 256 (scale .25).
// Separable triangle kernel, 8 taps at stride 4, weights {1,3,5,7,7,5,3,1}/8,
// normalized by sum of valid taps. One block per (plane, output-row).
// Block 0 zeroes the trunk's grid-barrier counters (stream-ordered before
// trunk_k, so every graph replay starts clean).
// ---------------------------------------------------------------------------
__global__ __launch_bounds__(256) void resize_k(const float* __restrict__ x,
                                                float* __restrict__ sm,
                                                unsigned* __restrict__ bar) {
    __shared__ float vsum[1024];
    const int blk = blockIdx.x;          // 24*256
    const int plane = blk >> 8;
    const int orow = blk & 255;
    const int t = threadIdx.x;
    if (blk == 0 && t < 8) bar[t] = 0u;

    const float W[8] = {0.125f,0.375f,0.625f,0.875f,0.875f,0.625f,0.375f,0.125f};
    const float* p = x + (size_t)plane * 1048576 + t * 4;
    const int r0 = 4 * orow - 2;
    float ax = 0.f, ay = 0.f, az = 0.f, aw = 0.f;
    if (r0 >= 0 && r0 + 7 <= 1023) {
        #pragma unroll
        for (int k = 0; k < 8; k++) {
            const float4 v = *(const float4*)(p + (r0 + k) * 1024);
            const float w = W[k] * 0.25f;
            ax = fmaf(v.x, w, ax); ay = fmaf(v.y, w, ay);
            az = fmaf(v.z, w, az); aw = fmaf(v.w, w, aw);
        }
    } else {
        float wsum = 0.f;
        #pragma unroll
        for (int k = 0; k < 8; k++) {
            const int r = r0 + k;
            if (r >= 0 && r < 1024) {
                const float4 v = *(const float4*)(p + r * 1024);
                ax = fmaf(v.x, W[k], ax); ay = fmaf(v.y, W[k], ay);
                az = fmaf(v.z, W[k], az); aw = fmaf(v.w, W[k], aw);
                wsum += W[k];
            }
        }
        const float inv = 1.f / wsum;
        ax *= inv; ay *= inv; az *= inv; aw *= inv;
    }
    vsum[4 * t + 0] = ax; vsum[4 * t + 1] = ay;
    vsum[4 * t + 2] = az; vsum[4 * t + 3] = aw;
    __syncthreads();

    const int c0 = 4 * t - 2;
    float acc = 0.f;
    if (c0 >= 0 && c0 + 7 <= 1023) {
        #pragma unroll
        for (int k = 0; k < 8; k++)
            acc = fmaf(vsum[c0 + k], W[k] * 0.25f, acc);
    } else {
        float wsum = 0.f;
        #pragma unroll
        for (int k = 0; k < 8; k++) {
            const int c = c0 + k;
            if (c >= 0 && c < 1024) { acc = fmaf(vsum[c], W[k], acc); wsum += W[k]; }
        }
        acc /= wsum;
    }
    sm[(size_t)blk * 256 + t] = acc;
}

// ---------------------------------------------------------------------------
// Lightweight grid barrier for the persistent trunk.
// Release fence once -> RELAXED agent add -> spin on RELAXED agent load
// (no per-poll cache invalidate!) with s_sleep backoff -> acquire fence once.
// ---------------------------------------------------------------------------
__device__ __forceinline__ void gb_arrive(unsigned* cnt) {
    __syncthreads();
    if (threadIdx.x == 0) {
        __threadfence();   // release: L2 writeback of this block's writes
        __hip_atomic_fetch_add(cnt, 1u, __ATOMIC_RELAXED, __HIP_MEMORY_SCOPE_AGENT);
    }
}
__device__ __forceinline__ void gb_wait(unsigned* cnt) {
    if (threadIdx.x == 0) {
        while (__hip_atomic_load(cnt, __ATOMIC_RELAXED, __HIP_MEMORY_SCOPE_AGENT) < (unsigned)NBLK)
            __builtin_amdgcn_s_sleep(8);
        __threadfence();   // acquire: invalidate stale cached lines
    }
    __syncthreads();
}
__device__ __forceinline__ void gridbar(unsigned* cnt) {
    gb_arrive(cnt);
    gb_wait(cnt);
}

// ---------------------------------------------------------------------------
// Shared scratch for the trunk phases (reused across phases).
// ---------------------------------------------------------------------------
struct TrunkSM {
    float wsm[2][576];        // staged (BN-folded) weights, max CIN=64
    float scs[64], shs[64];   // BN scale/shift of previous layer
    float wrow[2][64];        // raw weight row-sums (for folded constant)
    float cadd[2];
    float part[4][64][2];     // ci-split partials (conv5)
    float red[2][2][4];       // stats cross-warp reduce
    float sredS[256], sredQ[256];
};

// ---------------------------------------------------------------------------
// One conv layer as a phase of the persistent trunk kernel (NCO=2 fixed).
// Work item = (b, co-pair, pixel-tile); item = it*NBLK + blk.
// Partial stats: unique slot (b*COUT+co)*NTOUT + tile — plain stores.
// ---------------------------------------------------------------------------
template<int CIN, int COUT, int INW, int OUTW, int CISPLIT, int PIX, int TILES,
         int NTPREV, int NTOUT, int NITER, bool INBN, bool STATS, bool WRITE>
__device__ __forceinline__ void conv_phase(
    TrunkSM& s,
    const float* __restrict__ in, const float* __restrict__ w,
    const float* __restrict__ bias, const float* __restrict__ gam,
    const float* __restrict__ be, const float* __restrict__ pS,
    const float* __restrict__ pQ, float invN,
    float* __restrict__ out, float* __restrict__ pSo, float* __restrict__ pQo,
    int blk, int tid)
{
    constexpr int BLOCK = 256;
    constexpr int CPS = CIN / CISPLIT;
    constexpr int COG = COUT / 2;
    constexpr int NPIXV = OUTW * OUTW;
    const int p  = tid & (PIX - 1);
    const int cs = tid / PIX;

    if constexpr (INBN) {
        constexpr int GRP = BLOCK / CIN;
        constexpr int TERMS = 8 * NTPREV;
        const int ci = tid % CIN;
        const int gi = tid / CIN;
        float sv = 0.f, qv = 0.f;
        for (int j = gi; j < TERMS; j += GRP) {
            const int bb = j / NTPREV, tl = j - bb * NTPREV;
            const int a = (bb * CIN + ci) * NTPREV + tl;
            sv += pS[a]; qv += pQ[a];
        }
        s.sredS[gi * CIN + ci] = sv;
        s.sredQ[gi * CIN + ci] = qv;
        __syncthreads();
        if (tid < CIN) {
            float ts = 0.f, tq = 0.f;
            #pragma unroll
            for (int g2 = 0; g2 < GRP; g2++) {
                ts += s.sredS[g2 * CIN + tid];
                tq += s.sredQ[g2 * CIN + tid];
            }
            const float m = ts * invN;
            const float v = tq * invN - m * m;
            const float sc = gam[tid] * rsqrtf(v + 1e-5f);
            s.scs[tid] = sc;
            s.shs[tid] = be[tid] - m * sc;
        }
        __syncthreads();
    }

    for (int it = 0; it < NITER; ++it) {
        const int item = it * NBLK + blk;
        const int tile = item % TILES;
        const int rest = item / TILES;
        const int co0  = (rest % COG) * 2;
        const int b    = rest / COG;

        __syncthreads();   // protect wsm/cadd reuse across items
        for (int i = tid; i < 2 * CIN * 9; i += BLOCK) {
            int n = i / (CIN * 9), r = i - n * (CIN * 9), ci = r / 9;
            float wv = w[(co0 + n) * CIN * 9 + r];
            s.wsm[n][r] = INBN ? wv * s.scs[ci] : wv;
        }
        if constexpr (INBN) {
            for (int i = tid; i < 2 * CIN; i += BLOCK) {
                int n = i / CIN, ci = i - n * CIN;
                const float* wp = w + ((co0 + n) * CIN + ci) * 9;
                float sv = 0.f;
                #pragma unroll
                for (int k = 0; k < 9; k++) sv += wp[k];
                s.wrow[n][ci] = sv;
            }
        }
        __syncthreads();
        if (tid < 2) {
            float c = bias[co0 + tid];
            if constexpr (INBN) {
                for (int ci = 0; ci < CIN; ci++) c = fmaf(s.wrow[tid][ci], s.shs[ci], c);
            }
            s.cadd[tid] = c;
        }
        __syncthreads();

        const int pg = tile * PIX + p;
        float a0 = 0.f, a1 = 0.f;
        if (pg < NPIXV) {
            const int oh = pg / OUTW, ow = pg - oh * OUTW;
            const float* ib = in + ((size_t)(b * CIN) + cs * CPS) * (INW * INW)
                                 + (size_t)(2 * oh) * INW + 2 * ow;
            #pragma unroll 4
            for (int ci = 0; ci < CPS; ci++) {
                const float* ip = ib + (size_t)ci * (INW * INW);
                const int cw = (cs * CPS + ci) * 9;
                #pragma unroll
                for (int kh = 0; kh < 3; kh++) {
                    const float* r = ip + kh * INW;
                    #pragma unroll
                    for (int kw = 0; kw < 3; kw++) {
                        const float xv = r[kw];
                        a0 = fmaf(xv, s.wsm[0][cw + kh * 3 + kw], a0);
                        a1 = fmaf(xv, s.wsm[1][cw + kh * 3 + kw], a1);
                    }
                }
            }
        }

        float v0 = 0.f, v1 = 0.f;
        if constexpr (CISPLIT > 1) {
            s.part[cs][p][0] = a0; s.part[cs][p][1] = a1;
            __syncthreads();
        }
        if (cs == 0) {
            float s0 = a0, s1 = a1;
            if constexpr (CISPLIT > 1) {
                #pragma unroll
                for (int q = 1; q < CISPLIT; q++) { s0 += s.part[q][p][0]; s1 += s.part[q][p][1]; }
            }
            if (pg < NPIXV) {
                v0 = fmaxf(s0 + s.cadd[0], 0.f);
                v1 = fmaxf(s1 + s.cadd[1], 0.f);
                if constexpr (WRITE) {
                    out[(size_t)(b * COUT + co0) * NPIXV + pg] = v0;
                    out[(size_t)(b * COUT + co0 + 1) * NPIXV + pg] = v1;
                }
            }
        }
        if constexpr (STATS) {
            if (cs == 0) {
                float sA = v0, qA = v0 * v0, sB = v1, qB = v1 * v1;
                #pragma unroll
                for (int off = 32; off > 0; off >>= 1) {
                    sA += __shfl_down(sA, off); qA += __shfl_down(qA, off);
                    sB += __shfl_down(sB, off); qB += __shfl_down(qB, off);
                }
                if ((tid & 63) == 0) {
                    s.red[0][0][tid >> 6] = sA; s.red[0][1][tid >> 6] = qA;
                    s.red[1][0][tid >> 6] = sB; s.red[1][1][tid >> 6] = qB;
                }
            }
            __syncthreads();
            if (tid == 0) {
                float tsA = 0.f, tqA = 0.f, tsB = 0.f, tqB = 0.f;
                #pragma unroll
                for (int i = 0; i < PIX / 64; i++) {
                    tsA += s.red[0][0][i]; tqA += s.red[0][1][i];
                    tsB += s.red[1][0][i]; tqB += s.red[1][1][i];
                }
                pSo[(b * COUT + co0) * NTOUT + tile] = tsA;
                pQo[(b * COUT + co0) * NTOUT + tile] = tqA;
                pSo[(b * COUT + co0 + 1) * NTOUT + tile] = tsB;
                pQo[(b * COUT + co0 + 1) * NTOUT + tile] = tqB;
            }
        }
    }
}

// ---------------------------------------------------------------------------
// Persistent trunk: conv1..conv5 phases with lightweight grid barriers, then
// block 0 runs BN5 -> mean -> fc1 -> fc2 -> spline tail.
// Grid MUST be NBLK=256 blocks x 256 threads (1 block/CU, all co-resident).
// ---------------------------------------------------------------------------
__global__ __launch_bounds__(256) void trunk_k(
    const float* __restrict__ sm,
    const float* __restrict__ w1, const float* __restrict__ b1,
    const float* __restrict__ w2, const float* __restrict__ b2,
    const float* __restrict__ g2, const float* __restrict__ be2,
    const float* __restrict__ w3, const float* __restrict__ b3,
    const float* __restrict__ g3, const float* __restrict__ be3,
    const float* __restrict__ w4, const float* __restrict__ b4,
    const float* __restrict__ g4, const float* __restrict__ be4,
    const float* __restrict__ w5, const float* __restrict__ b5,
    const float* __restrict__ g5, const float* __restrict__ be5,
    const float* __restrict__ fc1w, const float* __restrict__ fc1b,
    const float* __restrict__ fc2w, const float* __restrict__ fc2b,
    float* __restrict__ h1, float* __restrict__ h2,
    float* __restrict__ h3, float* __restrict__ h4,
    float* __restrict__ pS2, float* __restrict__ pQ2,
    float* __restrict__ pS3, float* __restrict__ pQ3,
    float* __restrict__ pS4, float* __restrict__ pQ4,
    float* __restrict__ pS5, float* __restrict__ pQ5,
    float* __restrict__ coeff_out, float* __restrict__ splines_out,
    unsigned* __restrict__ bar)
{
    __shared__ TrunkSM s;
    __shared__ float fsc5[128], fsh5[128];
    __shared__ float fch[1024], fh1[1024];
    __shared__ float fysn[240];
    __shared__ float fcoef[24][36];

    const int blk = blockIdx.x;
    const int t = threadIdx.x;

    // conv1: 3->8, 256->127   items = 8b*4cg*64t = 2048
    conv_phase<3, 8, 256, 127, 1, 256, 64, 1, 1, 8, false, false, true>(
        s, sm, w1, b1, nullptr, nullptr, nullptr, nullptr, 0.f,
        h1, nullptr, nullptr, blk, t);
    gridbar(bar + 0);

    // conv2: 8->16, 127->63   items = 8*8*16 = 1024
    conv_phase<8, 16, 127, 63, 1, 256, 16, 1, 16, 4, false, true, true>(
        s, h1, w2, b2, nullptr, nullptr, nullptr, nullptr, 0.f,
        h2, pS2, pQ2, blk, t);
    gridbar(bar + 1);

    // conv3: 16->32, 63->31 (BN2)   items = 8*16*4 = 512
    conv_phase<16, 32, 63, 31, 1, 256, 4, 16, 4, 2, true, true, true>(
        s, h2, w3, b3, g2, be2, pS2, pQ2, 1.0f / 31752.0f,
        h3, pS3, pQ3, blk, t);
    gridbar(bar + 2);

    // conv4: 32->64, 31->15 (BN3)   items = 8*32*1 = 256
    conv_phase<32, 64, 31, 15, 1, 256, 1, 4, 1, 1, true, true, true>(
        s, h3, w4, b4, g3, be3, pS3, pQ3, 1.0f / 7688.0f,
        h4, pS4, pQ4, blk, t);
    gridbar(bar + 3);

    // conv5: 64->128, 15->7 (BN4), ci-split 4, stats only   items = 8*64 = 512
    conv_phase<64, 128, 15, 7, 4, 64, 1, 1, 1, 2, true, true, false>(
        s, h4, w5, b5, g4, be4, pS4, pQ4, 1.0f / 1800.0f,
        nullptr, pS5, pQ5, blk, t);

    // final barrier: non-zero blocks arrive and exit; block 0 waits, runs tail
    gb_arrive(bar + 4);
    if (blk != 0) return;
    gb_wait(bar + 4);

    // ---- fc1 / fc2 / spline tail (block 0 only) ----
    if (t < 128) {
        float sv = 0.f, qv = 0.f;
        #pragma unroll
        for (int b = 0; b < 8; b++) { sv += pS5[b * 128 + t]; qv += pQ5[b * 128 + t]; }
        float m = sv * (1.f / 392.f);
        float v = qv * (1.f / 392.f) - m * m;
        float sc = g5[t] * rsqrtf(v + 1e-5f);
        fsc5[t] = sc;
        fsh5[t] = be5[t] - m * sc;
    }
    __syncthreads();

    for (int i = t; i < 1024; i += 256) {
        int c = i & 127;
        fch[i] = fmaf(fsc5[c], pS5[i] * (1.f / 49.f), fsh5[c]);
    }
    __syncthreads();

    for (int i = t; i < 1024; i += 256) {
        int b = i >> 7, j = i & 127;
        float acc = fc1b[j];
        for (int c = 0; c < 128; c++)
            acc = fmaf(fch[(b << 7) + c], fc1w[(j << 7) + c], acc);
        fh1[i] = fmaxf(acc, 0.f);
    }
    __syncthreads();

    if (t < 240) {
        int b = t / 30, k = t % 30;
        float acc = fc2b[k];
        for (int j = 0; j < 128; j++)
            acc = fmaf(fh1[(b << 7) + j], fc2w[(k << 7) + j], acc);
        fysn[t] = acc + (float)(k % 10) * STEP_F;   // + identity ramp
    }
    __syncthreads();

    if (t < 24) {
        float y[10];
        #pragma unroll
        for (int i = 0; i < 10; i++) y[i] = fysn[t * 10 + i];
        // Thomas solve: M[i-1] + 4 M[i] + M[i+1] = 486*(y[i-1]-2y[i]+y[i+1])
        float rhs[9], cp[9], dp[9];
        #pragma unroll
        for (int i = 1; i <= 8; i++)
            rhs[i] = 486.f * (y[i - 1] - 2.f * y[i] + y[i + 1]);
        cp[1] = 0.25f; dp[1] = rhs[1] * 0.25f;
        #pragma unroll
        for (int i = 2; i <= 8; i++) {
            float m = 1.f / (4.f - cp[i - 1]);
            cp[i] = m;
            dp[i] = (rhs[i] - dp[i - 1]) * m;
        }
        float M[10];
        M[0] = 0.f; M[9] = 0.f;
        M[8] = dp[8];
        #pragma unroll
        for (int i = 7; i >= 1; i--) M[i] = dp[i] - cp[i] * M[i + 1];
        #pragma unroll
        for (int i = 0; i < 9; i++) {
            float a = (M[i + 1] - M[i]) * 1.5f;               // /(6h), h=1/9
            float bb = M[i] * 0.5f;
            float cc = (y[i + 1] - y[i]) * 9.f - (M[i + 1] + 2.f * M[i]) * (STEP_F / 6.f);
            float dd = y[i];
            fcoef[t][i] = a; fcoef[t][9 + i] = bb; fcoef[t][18 + i] = cc; fcoef[t][27 + i] = dd;
            coeff_out[t * 36 + i] = a;
            coeff_out[t * 36 + 9 + i] = bb;
            coeff_out[t * 36 + 18 + i] = cc;
            coeff_out[t * 36 + 27 + i] = dd;
        }
    }
    __syncthreads();

    for (int i = t; i < 24 * 255; i += 256) {
        int bc = i / 255, k = i - bc * 255;
        float xv = (float)k * (1.0f / 255.0f);
        float xi = floorf(xv * 9.0f);
        xi = fminf(fmaxf(xi, 0.f), 8.f);
        int ix = (int)xi;
        float xf = xv - xi * STEP_F;
        const float* cf = fcoef[bc];
        splines_out[i] = fmaf(fmaf(fmaf(cf[ix], xf, cf[9 + ix]), xf, cf[18 + ix]), xf, cf[27 + ix]);
    }
}

// ---------------------------------------------------------------------------
// Apply spline to full-res x. One block = 1024 consecutive floats.
// ---------------------------------------------------------------------------
__global__ __launch_bounds__(256) void apply_k(const float* __restrict__ x,
                                               const float* __restrict__ coeff,
                                               float* __restrict__ out)
{
    __shared__ float cf[36];
    const int blk = blockIdx.x;
    const int plane = blk >> 10;           // 1024 blocks per 1M-float plane
    const int t = threadIdx.x;
    if (t < 36) cf[t] = coeff[plane * 36 + t];
    __syncthreads();

    size_t base = (size_t)blk * 1024 + (size_t)t * 4;
    float4 v = *(const float4*)(x + base);
    f32x4 o;
    #pragma unroll
    for (int k = 0; k < 4; k++) {
        float xv = (k == 0) ? v.x : (k == 1) ? v.y : (k == 2) ? v.z : v.w;
        float xi = floorf(xv * 9.0f);
        xi = fminf(fmaxf(xi, 0.f), 8.f);
        int ix = (int)xi;
        float xf = xv - xi * STEP_F;
        o[k] = fmaf(fmaf(fmaf(cf[ix], xf, cf[9 + ix]), xf, cf[18 + ix]), xf, cf[27 + ix]);
    }
    __builtin_nontemporal_store(o, (f32x4*)(out + base));
}

// ---------------------------------------------------------------------------
extern "C" void kernel_launch(void* const* d_in, const int* in_sizes, int n_in,
                              void* d_out, int out_size, void* d_ws, size_t ws_size,
                              hipStream_t stream) {
    (void)in_sizes; (void)n_in; (void)out_size; (void)ws_size;

    const float* x    = (const float*)d_in[0];
    const float* w1   = (const float*)d_in[1];
    const float* b1   = (const float*)d_in[2];
    const float* w2   = (const float*)d_in[3];
    const float* b2   = (const float*)d_in[4];
    const float* g2   = (const float*)d_in[5];
    const float* be2  = (const float*)d_in[6];
    const float* w3   = (const float*)d_in[7];
    const float* b3   = (const float*)d_in[8];
    const float* g3   = (const float*)d_in[9];
    const float* be3  = (const float*)d_in[10];
    const float* w4   = (const float*)d_in[11];
    const float* b4   = (const float*)d_in[12];
    const float* g4   = (const float*)d_in[13];
    const float* be4  = (const float*)d_in[14];
    const float* w5   = (const float*)d_in[15];
    const float* b5   = (const float*)d_in[16];
    const float* g5   = (const float*)d_in[17];
    const float* be5  = (const float*)d_in[18];
    const float* fc1w = (const float*)d_in[19];
    const float* fc1b = (const float*)d_in[20];
    const float* fc2w = (const float*)d_in[21];
    const float* fc2b = (const float*)d_in[22];

    float* out = (float*)d_out;
    float* wsf = (float*)d_ws;

    // ws: per-block/per-item partials (fully overwritten every call)
    float* pS2 = wsf + 0;      // [8*16*16] = 2048
    float* pQ2 = wsf + 2048;
    float* pS3 = wsf + 4096;   // [8*32*4]  = 1024
    float* pQ3 = wsf + 5120;
    float* pS4 = wsf + 6144;   // [8*64*1]  = 512
    float* pQ4 = wsf + 6656;
    float* pS5 = wsf + 7168;   // [8*128]   = 1024  (spatial sums for fc)
    float* pQ5 = wsf + 8192;
    float* coeff = wsf + 9216; // [24*36]
    unsigned* bar = (unsigned*)(wsf + 10240);  // 8 barrier counters (zeroed by resize)

    // big intermediates in d_out's first ~14 MB (overwritten by apply_k)
    float* sm  = out;                  // 24*256*256  = 1572864
    float* h1  = out + 1572864;        // 8*8*127*127 = 1032256
    float* h2  = out + 2605120;        // 8*16*63*63  =  508032
    float* h3  = out + 3113152;        // 8*32*31*31  =  246016
    float* h4  = out + 3359168;        // 8*64*15*15  =  115200

    resize_k<<<6144, 256, 0, stream>>>(x, sm, bar);

    trunk_k<<<NBLK, 256, 0, stream>>>(
        sm,
        w1, b1, w2, b2, g2, be2, w3, b3, g3, be3,
        w4, b4, g4, be4, w5, b5, g5, be5,
        fc1w, fc1b, fc2w, fc2b,
        h1, h2, h3, h4,
        pS2, pQ2, pS3, pQ3, pS4, pQ4, pS5, pQ5,
        coeff, out + SPLINE_OFF, bar);

    apply_k<<<24576, 256, 0, stream>>>(x, coeff, out);
}

// Round 8
// 145.066 us; speedup vs baseline: 1.5607x; 1.5607x over previous
//
#include <hip/hip_runtime.h>

#define SPLINE_OFF 25165824   // splines output offset (6120 floats follow)
#define STEP_F (1.0f/9.0f)

typedef float f32x4 __attribute__((ext_vector_type(4)));

// ---------------------------------------------------------------------------
// Resize: jax.image.resize bilinear antialias 1024->256 (scale .25), separable
// triangle kernel {1,3,5,7,7,5,3,1}/8 at stride 4, renormalized at edges.
// Each block produces TWO output rows of one plane (reads 12 input rows
// instead of 2x8). Interior fast path keeps the reference FMA order.
// ---------------------------------------------------------------------------
__global__ __launch_bounds__(256) void resize_k(const float* __restrict__ x,
                                                float* __restrict__ sm) {
    __shared__ float vs[2][1024];
    const int blk = blockIdx.x;          // 24*128
    const int plane = blk >> 7;
    const int orA = (blk & 127) * 2;     // output rows orA, orA+1
    const int t = threadIdx.x;

    const float W[8] = {0.125f,0.375f,0.625f,0.875f,0.875f,0.625f,0.375f,0.125f};
    const float* p = x + (size_t)plane * 1048576 + t * 4;
    const int rA = 4 * orA - 2;          // A: rows rA..rA+7; B: rA+4..rA+11

    float a0x=0.f,a0y=0.f,a0z=0.f,a0w=0.f;
    float a1x=0.f,a1y=0.f,a1z=0.f,a1w=0.f;

    if (rA >= 0 && rA + 11 <= 1023) {
        #pragma unroll
        for (int k = 0; k < 12; k++) {
            const float4 v = *(const float4*)(p + (size_t)(rA + k) * 1024);
            if (k < 8) {
                const float w = W[k] * 0.25f;
                a0x = fmaf(v.x, w, a0x); a0y = fmaf(v.y, w, a0y);
                a0z = fmaf(v.z, w, a0z); a0w = fmaf(v.w, w, a0w);
            }
            if (k >= 4) {
                const float w = W[k - 4] * 0.25f;
                a1x = fmaf(v.x, w, a1x); a1y = fmaf(v.y, w, a1y);
                a1z = fmaf(v.z, w, a1z); a1w = fmaf(v.w, w, a1w);
            }
        }
    } else {
        #pragma unroll
        for (int o = 0; o < 2; o++) {
            const int r0 = 4 * (orA + o) - 2;
            float bx=0.f,by=0.f,bz=0.f,bw=0.f,wsum=0.f;
            #pragma unroll
            for (int k = 0; k < 8; k++) {
                const int r = r0 + k;
                if (r >= 0 && r < 1024) {
                    const float4 v = *(const float4*)(p + (size_t)r * 1024);
                    bx = fmaf(v.x, W[k], bx); by = fmaf(v.y, W[k], by);
                    bz = fmaf(v.z, W[k], bz); bw = fmaf(v.w, W[k], bw);
                    wsum += W[k];
                }
            }
            const float inv = 1.f / wsum;
            if (o == 0) { a0x=bx*inv; a0y=by*inv; a0z=bz*inv; a0w=bw*inv; }
            else        { a1x=bx*inv; a1y=by*inv; a1z=bz*inv; a1w=bw*inv; }
        }
    }
    vs[0][4*t+0]=a0x; vs[0][4*t+1]=a0y; vs[0][4*t+2]=a0z; vs[0][4*t+3]=a0w;
    vs[1][4*t+0]=a1x; vs[1][4*t+1]=a1y; vs[1][4*t+2]=a1z; vs[1][4*t+3]=a1w;
    __syncthreads();

    const int c0 = 4 * t - 2;
    #pragma unroll
    for (int o = 0; o < 2; o++) {
        float acc = 0.f;
        if (c0 >= 0 && c0 + 7 <= 1023) {
            #pragma unroll
            for (int k = 0; k < 8; k++)
                acc = fmaf(vs[o][c0 + k], W[k] * 0.25f, acc);
        } else {
            float wsum = 0.f;
            #pragma unroll
            for (int k = 0; k < 8; k++) {
                const int c = c0 + k;
                if (c >= 0 && c < 1024) { acc = fmaf(vs[o][c], W[k], acc); wsum += W[k]; }
            }
            acc /= wsum;
        }
        sm[((size_t)plane * 256 + orA + o) * 256 + t] = acc;
    }
}

// ---------------------------------------------------------------------------
// Fused conv1+conv2 (no BN between them, purely local dependency).
// One block per (8x8 conv2-tile, batch): stage sm halo tile (35x35x3) in LDS,
// compute conv1 (17x17x8, ReLU) into LDS, then conv2 (+b2, ReLU) + per-tile
// BN2 partial stats (race-free slot per (b,co,tile)).
// ---------------------------------------------------------------------------
__global__ __launch_bounds__(256) void c1c2_k(
    const float* __restrict__ sm,
    const float* __restrict__ w1, const float* __restrict__ b1,
    const float* __restrict__ w2, const float* __restrict__ b2,
    float* __restrict__ h2, float* __restrict__ pS2, float* __restrict__ pQ2)
{
    __shared__ float smT[3 * 1225];   // [ch][35][35]
    __shared__ float c1T[8 * 289];    // [co][17][17]
    __shared__ float w1s[216];
    __shared__ float w2s[1152];
    __shared__ float bs[24];          // b1[0..7], b2[8..23]

    const int tile = blockIdx.x;      // 0..63
    const int b    = blockIdx.y;      // 0..7
    const int tx = tile & 7, ty = tile >> 3;
    const int R0 = ty * 8, C0 = tx * 8;
    const int t = threadIdx.x;

    if (t < 216) w1s[t] = w1[t];
    for (int i = t; i < 1152; i += 256) w2s[i] = w2[i];
    if (t < 8) bs[t] = b1[t];
    else if (t < 24) bs[t] = b2[t - 8];

    // stage sm tile: rows 4R0..+34, cols 4C0..+34 (OOB -> 0, feeds only
    // invalid outputs)
    const int r0 = 4 * R0, c0 = 4 * C0;
    for (int i = t; i < 3675; i += 256) {
        const int ch = i / 1225, rem = i - ch * 1225;
        const int r = rem / 35, c = rem - r * 35;
        const int gr = r0 + r, gc = c0 + c;
        float v = 0.f;
        if (gr < 256 && gc < 256)
            v = sm[((size_t)(b * 3 + ch) << 16) + (gr << 8) + gc];
        smT[i] = v;
    }
    __syncthreads();

    // conv1: 17x17 x 8co from smT
    for (int i = t; i < 2312; i += 256) {
        const int co = i / 289, pp = i - co * 289;
        const int r = pp / 17, c = pp - r * 17;
        float acc = bs[co];
        #pragma unroll
        for (int ch = 0; ch < 3; ch++) {
            const float* sp = &smT[ch * 1225 + (2 * r) * 35 + 2 * c];
            const float* wp = &w1s[co * 27 + ch * 9];
            #pragma unroll
            for (int kh = 0; kh < 3; kh++) {
                acc = fmaf(sp[kh * 35 + 0], wp[kh * 3 + 0], acc);
                acc = fmaf(sp[kh * 35 + 1], wp[kh * 3 + 1], acc);
                acc = fmaf(sp[kh * 35 + 2], wp[kh * 3 + 2], acc);
            }
        }
        c1T[i] = fmaxf(acc, 0.f);
    }
    __syncthreads();

    // conv2: thread = (pixel 0..63, cog 0..3); 4 channels per thread
    const int px = t & 63, cog = t >> 6;
    const int pr = px >> 3, pc = px & 7;
    const bool valid = (R0 + pr < 63) && (C0 + pc < 63);
    float vals[4];
    #pragma unroll
    for (int k = 0; k < 4; k++) {
        const int co = cog * 4 + k;
        float acc = bs[8 + co];
        #pragma unroll
        for (int ci = 0; ci < 8; ci++) {
            const float* cp = &c1T[ci * 289 + (2 * pr) * 17 + 2 * pc];
            const float* wp = &w2s[co * 72 + ci * 9];
            #pragma unroll
            for (int kh = 0; kh < 3; kh++) {
                acc = fmaf(cp[kh * 17 + 0], wp[kh * 3 + 0], acc);
                acc = fmaf(cp[kh * 17 + 1], wp[kh * 3 + 1], acc);
                acc = fmaf(cp[kh * 17 + 2], wp[kh * 3 + 2], acc);
            }
        }
        const float v = valid ? fmaxf(acc, 0.f) : 0.f;
        vals[k] = v;
        if (valid)
            h2[(size_t)(b * 16 + co) * 3969 + (R0 + pr) * 63 + (C0 + pc)] = v;
    }
    // per-tile stats: the 64 pixels of a cog group are exactly one wave
    #pragma unroll
    for (int k = 0; k < 4; k++) {
        float s = vals[k], q = vals[k] * vals[k];
        #pragma unroll
        for (int off = 32; off > 0; off >>= 1) {
            s += __shfl_down(s, off);
            q += __shfl_down(q, off);
        }
        if (px == 0) {
            const int co = cog * 4 + k;
            pS2[(b * 16 + co) * 64 + tile] = s;
            pQ2[(b * 16 + co) * 64 + tile] = q;
        }
    }
}

// ---------------------------------------------------------------------------
// Direct 3x3 stride-2 VALID conv + bias + ReLU (conv3/4/5).  No atomics:
//  - INBN: previous layer's BN derived by reducing its per-block partials,
//    folded into staged weights: conv(sc*x+sh) = conv_{w*sc}(x) + C.
//  - STATS: block-reduced per-channel sum/sumsq -> unique partial slot.
//  - NCO=2; CISPLIT-way ci-split with LDS reduce; WRITE=false for conv5.
// Grid: (NTOUT, B * COUT/2). Block: PIX*CISPLIT threads.
// ---------------------------------------------------------------------------
template<int CIN, int COUT, int INW, int OUTW, int CISPLIT, int PIX,
         int NTPREV, int NTOUT, bool INBN, bool STATS, bool WRITE>
__global__ __launch_bounds__(PIX * CISPLIT) void conv_k(
    const float* __restrict__ in, const float* __restrict__ w,
    const float* __restrict__ bias,
    const float* __restrict__ gam, const float* __restrict__ be,
    const float* __restrict__ pS, const float* __restrict__ pQ, float invN,
    float* __restrict__ out,
    float* __restrict__ pSo, float* __restrict__ pQo)
{
    constexpr int BLOCK = PIX * CISPLIT;
    constexpr int CPS = CIN / CISPLIT;
    constexpr int COG = COUT / 2;

    __shared__ float wsm[2][CIN * 9];
    __shared__ float scs[CIN], shs[CIN];
    __shared__ float wrow[2][CIN];
    __shared__ float cadd[2];
    __shared__ float part[CISPLIT][PIX][2];
    __shared__ float red[2][2][PIX / 64];
    __shared__ float sredS[BLOCK], sredQ[BLOCK];

    const int tid = threadIdx.x;
    const int p   = tid & (PIX - 1);
    const int cs  = tid / PIX;
    const int bc  = blockIdx.y;
    const int b   = bc / COG;
    const int co0 = (bc % COG) * 2;

    if constexpr (INBN) {
        constexpr int GRP = BLOCK / CIN;
        constexpr int TERMS = 8 * NTPREV;
        const int ci = tid % CIN;
        const int gi = tid / CIN;
        float s = 0.f, q = 0.f;
        for (int j = gi; j < TERMS; j += GRP) {
            const int bb = j / NTPREV, tl = j - bb * NTPREV;
            const int a = (bb * CIN + ci) * NTPREV + tl;
            s += pS[a]; q += pQ[a];
        }
        sredS[gi * CIN + ci] = s;
        sredQ[gi * CIN + ci] = q;
        __syncthreads();
        if (tid < CIN) {
            float ts = 0.f, tq = 0.f;
            #pragma unroll
            for (int g2 = 0; g2 < GRP; g2++) {
                ts += sredS[g2 * CIN + tid];
                tq += sredQ[g2 * CIN + tid];
            }
            const float m = ts * invN;
            const float v = tq * invN - m * m;
            const float sc = gam[tid] * rsqrtf(v + 1e-5f);
            scs[tid] = sc;
            shs[tid] = be[tid] - m * sc;
        }
        __syncthreads();
    }

    for (int i = tid; i < 2 * CIN * 9; i += BLOCK) {
        const int n = i / (CIN * 9), r = i - n * (CIN * 9), ci = r / 9;
        const float wv = w[(co0 + n) * CIN * 9 + r];
        wsm[n][r] = INBN ? wv * scs[ci] : wv;
    }
    if constexpr (INBN) {
        for (int i = tid; i < 2 * CIN; i += BLOCK) {
            const int n = i / CIN, ci = i - n * CIN;
            const float* wp = w + ((co0 + n) * CIN + ci) * 9;
            float s = 0.f;
            #pragma unroll
            for (int k = 0; k < 9; k++) s += wp[k];
            wrow[n][ci] = s;
        }
    }
    __syncthreads();
    if (tid < 2) {
        float c = bias[co0 + tid];
        if constexpr (INBN) {
            for (int ci = 0; ci < CIN; ci++) c = fmaf(wrow[tid][ci], shs[ci], c);
        }
        cadd[tid] = c;
    }
    __syncthreads();

    const int npix = OUTW * OUTW;
    const int pg = blockIdx.x * PIX + p;
    float a0 = 0.f, a1 = 0.f;
    if (pg < npix) {
        const int oh = pg / OUTW, ow = pg - oh * OUTW;
        const float* ib = in + ((size_t)(b * CIN) + cs * CPS) * (INW * INW)
                             + (size_t)(2 * oh) * INW + 2 * ow;
        #pragma unroll 4
        for (int ci = 0; ci < CPS; ci++) {
            const float* ip = ib + (size_t)ci * (INW * INW);
            const int cw = (cs * CPS + ci) * 9;
            #pragma unroll
            for (int kh = 0; kh < 3; kh++) {
                const float* r = ip + kh * INW;
                #pragma unroll
                for (int kw = 0; kw < 3; kw++) {
                    const float xv = r[kw];
                    a0 = fmaf(xv, wsm[0][cw + kh * 3 + kw], a0);
                    a1 = fmaf(xv, wsm[1][cw + kh * 3 + kw], a1);
                }
            }
        }
    }

    float v0 = 0.f, v1 = 0.f;
    if constexpr (CISPLIT > 1) {
        part[cs][p][0] = a0; part[cs][p][1] = a1;
        __syncthreads();
    }
    if (cs == 0) {
        float s0 = a0, s1 = a1;
        if constexpr (CISPLIT > 1) {
            #pragma unroll
            for (int q = 1; q < CISPLIT; q++) { s0 += part[q][p][0]; s1 += part[q][p][1]; }
        }
        if (pg < npix) {
            v0 = fmaxf(s0 + cadd[0], 0.f);
            v1 = fmaxf(s1 + cadd[1], 0.f);
            if constexpr (WRITE) {
                out[(size_t)(b * COUT + co0) * npix + pg] = v0;
                out[(size_t)(b * COUT + co0 + 1) * npix + pg] = v1;
            }
        }
    }

    if constexpr (STATS) {
        if (cs == 0) {
            float sA = v0, qA = v0 * v0, sB = v1, qB = v1 * v1;
            #pragma unroll
            for (int off = 32; off > 0; off >>= 1) {
                sA += __shfl_down(sA, off); qA += __shfl_down(qA, off);
                sB += __shfl_down(sB, off); qB += __shfl_down(qB, off);
            }
            if ((tid & 63) == 0) {
                red[0][0][tid >> 6] = sA; red[0][1][tid >> 6] = qA;
                red[1][0][tid >> 6] = sB; red[1][1][tid >> 6] = qB;
            }
        }
        __syncthreads();
        if (tid == 0) {
            float tsA = 0.f, tqA = 0.f, tsB = 0.f, tqB = 0.f;
            #pragma unroll
            for (int i = 0; i < PIX / 64; i++) {
                tsA += red[0][0][i]; tqA += red[0][1][i];
                tsB += red[1][0][i]; tqB += red[1][1][i];
            }
            pSo[(b * COUT + co0) * NTOUT + blockIdx.x] = tsA;
            pQo[(b * COUT + co0) * NTOUT + blockIdx.x] = tqA;
            pSo[(b * COUT + co0 + 1) * NTOUT + blockIdx.x] = tsB;
            pQo[(b * COUT + co0 + 1) * NTOUT + blockIdx.x] = tqB;
        }
    }
}

// ---------------------------------------------------------------------------
// Single-block: BN5 (from conv5 partials) -> spatial mean -> fc1(ReLU) -> fc2
// -> +identity -> natural cubic spline (Thomas solve) -> coeffs + splines.
// ---------------------------------------------------------------------------
__global__ __launch_bounds__(256) void fc_spline_k(
    const float* __restrict__ pS5, const float* __restrict__ pQ5,
    const float* __restrict__ g5, const float* __restrict__ be5,
    const float* __restrict__ fc1w, const float* __restrict__ fc1b,
    const float* __restrict__ fc2w, const float* __restrict__ fc2b,
    float* __restrict__ coeff_out, float* __restrict__ splines_out)
{
    __shared__ float sc5[128], sh5[128];
    __shared__ float h[1024];
    __shared__ float h1v[1024];
    __shared__ float ysn[240];
    __shared__ float coef[24][36];

    const int t = threadIdx.x;

    if (t < 128) {
        float s = 0.f, q = 0.f;
        #pragma unroll
        for (int b = 0; b < 8; b++) { s += pS5[b * 128 + t]; q += pQ5[b * 128 + t]; }
        float m = s * (1.f / 392.f);
        float v = q * (1.f / 392.f) - m * m;
        float sc = g5[t] * rsqrtf(v + 1e-5f);
        sc5[t] = sc;
        sh5[t] = be5[t] - m * sc;
    }
    __syncthreads();

    for (int i = t; i < 1024; i += 256) {
        int c = i & 127;
        h[i] = fmaf(sc5[c], pS5[i] * (1.f / 49.f), sh5[c]);
    }
    __syncthreads();

    for (int i = t; i < 1024; i += 256) {
        int b = i >> 7, j = i & 127;
        float acc = fc1b[j];
        for (int c = 0; c < 128; c++)
            acc = fmaf(h[(b << 7) + c], fc1w[(j << 7) + c], acc);
        h1v[i] = fmaxf(acc, 0.f);
    }
    __syncthreads();

    if (t < 240) {
        int b = t / 30, k = t % 30;
        float acc = fc2b[k];
        for (int j = 0; j < 128; j++)
            acc = fmaf(h1v[(b << 7) + j], fc2w[(k << 7) + j], acc);
        ysn[t] = acc + (float)(k % 10) * STEP_F;
    }
    __syncthreads();

    if (t < 24) {
        float y[10];
        #pragma unroll
        for (int i = 0; i < 10; i++) y[i] = ysn[t * 10 + i];
        float rhs[9], cp[9], dp[9];
        #pragma unroll
        for (int i = 1; i <= 8; i++)
            rhs[i] = 486.f * (y[i - 1] - 2.f * y[i] + y[i + 1]);
        cp[1] = 0.25f; dp[1] = rhs[1] * 0.25f;
        #pragma unroll
        for (int i = 2; i <= 8; i++) {
            float m = 1.f / (4.f - cp[i - 1]);
            cp[i] = m;
            dp[i] = (rhs[i] - dp[i - 1]) * m;
        }
        float M[10];
        M[0] = 0.f; M[9] = 0.f;
        M[8] = dp[8];
        #pragma unroll
        for (int i = 7; i >= 1; i--) M[i] = dp[i] - cp[i] * M[i + 1];
        #pragma unroll
        for (int i = 0; i < 9; i++) {
            float a = (M[i + 1] - M[i]) * 1.5f;
            float bb = M[i] * 0.5f;
            float cc = (y[i + 1] - y[i]) * 9.f - (M[i + 1] + 2.f * M[i]) * (STEP_F / 6.f);
            float dd = y[i];
            coef[t][i] = a; coef[t][9 + i] = bb; coef[t][18 + i] = cc; coef[t][27 + i] = dd;
            coeff_out[t * 36 + i] = a;
            coeff_out[t * 36 + 9 + i] = bb;
            coeff_out[t * 36 + 18 + i] = cc;
            coeff_out[t * 36 + 27 + i] = dd;
        }
    }
    __syncthreads();

    for (int i = t; i < 24 * 255; i += 256) {
        int bc = i / 255, k = i - bc * 255;
        float xv = (float)k * (1.0f / 255.0f);
        float xi = floorf(xv * 9.0f);
        xi = fminf(fmaxf(xi, 0.f), 8.f);
        int ix = (int)xi;
        float xf = xv - xi * STEP_F;
        const float* cf = coef[bc];
        splines_out[i] = fmaf(fmaf(fmaf(cf[ix], xf, cf[9 + ix]), xf, cf[18 + ix]), xf, cf[27 + ix]);
    }
}

// ---------------------------------------------------------------------------
// Apply spline to full-res x. One block = 1024 consecutive floats.
// ---------------------------------------------------------------------------
__global__ __launch_bounds__(256) void apply_k(const float* __restrict__ x,
                                               const float* __restrict__ coeff,
                                               float* __restrict__ out)
{
    __shared__ float cf[36];
    const int blk = blockIdx.x;
    const int plane = blk >> 10;
    const int t = threadIdx.x;
    if (t < 36) cf[t] = coeff[plane * 36 + t];
    __syncthreads();

    size_t base = (size_t)blk * 1024 + (size_t)t * 4;
    float4 v = *(const float4*)(x + base);
    f32x4 o;
    #pragma unroll
    for (int k = 0; k < 4; k++) {
        float xv = (k == 0) ? v.x : (k == 1) ? v.y : (k == 2) ? v.z : v.w;
        float xi = floorf(xv * 9.0f);
        xi = fminf(fmaxf(xi, 0.f), 8.f);
        int ix = (int)xi;
        float xf = xv - xi * STEP_F;
        o[k] = fmaf(fmaf(fmaf(cf[ix], xf, cf[9 + ix]), xf, cf[18 + ix]), xf, cf[27 + ix]);
    }
    __builtin_nontemporal_store(o, (f32x4*)(out + base));
}

// ---------------------------------------------------------------------------
extern "C" void kernel_launch(void* const* d_in, const int* in_sizes, int n_in,
                              void* d_out, int out_size, void* d_ws, size_t ws_size,
                              hipStream_t stream) {
    (void)in_sizes; (void)n_in; (void)out_size; (void)ws_size;

    const float* x    = (const float*)d_in[0];
    const float* w1   = (const float*)d_in[1];
    const float* b1   = (const float*)d_in[2];
    const float* w2   = (const float*)d_in[3];
    const float* b2   = (const float*)d_in[4];
    const float* g2   = (const float*)d_in[5];
    const float* be2  = (const float*)d_in[6];
    const float* w3   = (const float*)d_in[7];
    const float* b3   = (const float*)d_in[8];
    const float* g3   = (const float*)d_in[9];
    const float* be3  = (const float*)d_in[10];
    const float* w4   = (const float*)d_in[11];
    const float* b4   = (const float*)d_in[12];
    const float* g4   = (const float*)d_in[13];
    const float* be4  = (const float*)d_in[14];
    const float* w5   = (const float*)d_in[15];
    const float* b5   = (const float*)d_in[16];
    const float* g5   = (const float*)d_in[17];
    const float* be5  = (const float*)d_in[18];
    const float* fc1w = (const float*)d_in[19];
    const float* fc1b = (const float*)d_in[20];
    const float* fc2w = (const float*)d_in[21];
    const float* fc2b = (const float*)d_in[22];

    float* out = (float*)d_out;
    float* wsf = (float*)d_ws;

    // ws: per-block partials (fully overwritten every call; no atomics)
    float* pS2 = wsf + 0;       // [8*16*64] = 8192
    float* pQ2 = wsf + 8192;
    float* pS3 = wsf + 16384;   // [8*32*4]  = 1024
    float* pQ3 = wsf + 17408;
    float* pS4 = wsf + 18432;   // [8*64]    = 512
    float* pQ4 = wsf + 18944;
    float* pS5 = wsf + 19456;   // [8*128]   = 1024 (spatial sums for fc)
    float* pQ5 = wsf + 20480;
    float* coeff = wsf + 21504; // [24*36]

    // big intermediates in d_out (overwritten by apply_k)
    float* sm  = out;                  // 24*256*256 = 1572864
    float* h2  = out + 1572864;        // 8*16*63*63 = 508032
    float* h3  = out + 2080896;        // 8*32*31*31 = 246016
    float* h4  = out + 2326912;        // 8*64*15*15 = 115200

    resize_k<<<3072, 256, 0, stream>>>(x, sm);

    // conv1+conv2 fused (LDS tiles), writes h2 + BN2 partials
    c1c2_k<<<dim3(64, 8), 256, 0, stream>>>(sm, w1, b1, w2, b2, h2, pS2, pQ2);

    // conv3: 16->32, 63->31 (BN2 from partials; ci-split 2)
    conv_k<16, 32, 63, 31, 2, 256, 64, 4, true, true, true>
        <<<dim3(4, 128), 512, 0, stream>>>(h2, w3, b3, g2, be2,
                                           pS2, pQ2, 1.0f / 31752.0f,
                                           h3, pS3, pQ3);
    // conv4: 32->64, 31->15 (BN3; ci-split 4)
    conv_k<32, 64, 31, 15, 4, 256, 4, 1, true, true, true>
        <<<dim3(1, 256), 1024, 0, stream>>>(h3, w4, b4, g3, be3,
                                            pS3, pQ3, 1.0f / 7688.0f,
                                            h4, pS4, pQ4);
    // conv5: 64->128, 15->7 (BN4; ci-split 8; stats only, no store)
    conv_k<64, 128, 15, 7, 8, 64, 1, 1, true, true, false>
        <<<dim3(1, 512), 512, 0, stream>>>(h4, w5, b5, g4, be4,
                                           pS4, pQ4, 1.0f / 1800.0f,
                                           nullptr, pS5, pQ5);

    fc_spline_k<<<1, 256, 0, stream>>>(pS5, pQ5, g5, be5,
                                       fc1w, fc1b, fc2w, fc2b,
                                       coeff, out + SPLINE_OFF);

    apply_k<<<24576, 256, 0, stream>>>(x, coeff, out);
}

// Round 9
// 129.925 us; speedup vs baseline: 1.7426x; 1.1165x over previous
//
#include <hip/hip_runtime.h>

#define SPLINE_OFF 25165824   // splines output offset (6120 floats follow)
#define STEP_F (1.0f/9.0f)

typedef float f32x4 __attribute__((ext_vector_type(4)));

// ---------------------------------------------------------------------------
// Resize: jax.image.resize bilinear antialias 1024->256 (scale .25), separable
// triangle kernel {1,3,5,7,7,5,3,1}/8 at stride 4, renormalized at edges.
// Each block produces FOUR output rows of one plane: reads rows rb..rb+19
// once (float4/thread), accumulates each row into the (up to 2) output
// windows it belongs to, in ascending-k order per output (= reference FMA
// order). Edge blocks (orA=0, 252) use the per-row renormalized fallback.
// Block 0 zeroes the conv5 finale counter (stream-ordered before conv5).
// ---------------------------------------------------------------------------
__global__ __launch_bounds__(256) void resize_k(const float* __restrict__ x,
                                                float* __restrict__ sm,
                                                unsigned* __restrict__ ctr) {
    __shared__ float vs[4][1024];
    const int blk = blockIdx.x;          // 24*64
    const int plane = blk >> 6;
    const int orA = (blk & 63) * 4;      // output rows orA..orA+3
    const int t = threadIdx.x;
    if (blk == 0 && t == 0) ctr[0] = 0u;

    const float W[8] = {0.125f,0.375f,0.625f,0.875f,0.875f,0.625f,0.375f,0.125f};
    const float* p = x + (size_t)plane * 1048576 + t * 4;
    const int rb = 4 * orA - 2;

    float acc[4][4];
    #pragma unroll
    for (int o = 0; o < 4; o++)
        #pragma unroll
        for (int c = 0; c < 4; c++) acc[o][c] = 0.f;

    if (rb >= 0 && rb + 19 <= 1023) {
        #pragma unroll
        for (int k = 0; k < 20; k++) {
            const float4 v = *(const float4*)(p + (size_t)(rb + k) * 1024);
            #pragma unroll
            for (int o = 0; o < 4; o++) {
                const int j = k - 4 * o;
                if (j >= 0 && j < 8) {
                    const float w = W[j] * 0.25f;
                    acc[o][0] = fmaf(v.x, w, acc[o][0]);
                    acc[o][1] = fmaf(v.y, w, acc[o][1]);
                    acc[o][2] = fmaf(v.z, w, acc[o][2]);
                    acc[o][3] = fmaf(v.w, w, acc[o][3]);
                }
            }
        }
    } else {
        #pragma unroll
        for (int o = 0; o < 4; o++) {
            const int r0 = 4 * (orA + o) - 2;
            float bx=0.f,by=0.f,bz=0.f,bw=0.f,wsum=0.f;
            #pragma unroll
            for (int k = 0; k < 8; k++) {
                const int r = r0 + k;
                if (r >= 0 && r < 1024) {
                    const float4 v = *(const float4*)(p + (size_t)r * 1024);
                    bx = fmaf(v.x, W[k], bx); by = fmaf(v.y, W[k], by);
                    bz = fmaf(v.z, W[k], bz); bw = fmaf(v.w, W[k], bw);
                    wsum += W[k];
                }
            }
            const float inv = 1.f / wsum;
            acc[o][0]=bx*inv; acc[o][1]=by*inv; acc[o][2]=bz*inv; acc[o][3]=bw*inv;
        }
    }
    #pragma unroll
    for (int o = 0; o < 4; o++) {
        vs[o][4*t+0]=acc[o][0]; vs[o][4*t+1]=acc[o][1];
        vs[o][4*t+2]=acc[o][2]; vs[o][4*t+3]=acc[o][3];
    }
    __syncthreads();

    const int c0 = 4 * t - 2;
    #pragma unroll
    for (int o = 0; o < 4; o++) {
        float a = 0.f;
        if (c0 >= 0 && c0 + 7 <= 1023) {
            #pragma unroll
            for (int k = 0; k < 8; k++)
                a = fmaf(vs[o][c0 + k], W[k] * 0.25f, a);
        } else {
            float wsum = 0.f;
            #pragma unroll
            for (int k = 0; k < 8; k++) {
                const int c = c0 + k;
                if (c >= 0 && c < 1024) { a = fmaf(vs[o][c], W[k], a); wsum += W[k]; }
            }
            a /= wsum;
        }
        sm[((size_t)plane * 256 + orA + o) * 256 + t] = a;
    }
}

// ---------------------------------------------------------------------------
// Direct 3x3 stride-2 VALID conv + bias + ReLU (round-6 version).  No atomics:
//  - INBN: previous layer's BN derived by reducing its per-block partials,
//    folded into staged weights: conv(sc*x+sh) = conv_{w*sc}(x) + C.
//  - STATS: block-reduced per-channel sum/sumsq -> unique partial slot.
//  - NCO=2 fixed; CISPLIT-way ci-split with LDS reduce.
// Grid: (NTOUT, B * COUT/2). Block: PIX*CISPLIT threads.
// ---------------------------------------------------------------------------
template<int CIN, int COUT, int INW, int OUTW, int CISPLIT, int PIX,
         int NTPREV, int NTOUT, bool INBN, bool STATS, bool WRITE>
__global__ __launch_bounds__(PIX * CISPLIT) void conv_k(
    const float* __restrict__ in, const float* __restrict__ w,
    const float* __restrict__ bias,
    const float* __restrict__ gam, const float* __restrict__ be,
    const float* __restrict__ pS, const float* __restrict__ pQ, float invN,
    float* __restrict__ out,
    float* __restrict__ pSo, float* __restrict__ pQo)
{
    constexpr int BLOCK = PIX * CISPLIT;
    constexpr int CPS = CIN / CISPLIT;
    constexpr int COG = COUT / 2;

    __shared__ float wsm[2][CIN * 9];
    __shared__ float scs[CIN], shs[CIN];
    __shared__ float wrow[2][CIN];
    __shared__ float cadd[2];
    __shared__ float part[CISPLIT][PIX][2];
    __shared__ float red[2][2][PIX / 64];
    __shared__ float sredS[BLOCK], sredQ[BLOCK];

    const int tid = threadIdx.x;
    const int p   = tid & (PIX - 1);
    const int cs  = tid / PIX;
    const int bc  = blockIdx.y;
    const int b   = bc / COG;
    const int co0 = (bc % COG) * 2;

    if constexpr (INBN) {
        constexpr int GRP = BLOCK / CIN;
        constexpr int TERMS = 8 * NTPREV;
        const int ci = tid % CIN;
        const int gi = tid / CIN;
        float s = 0.f, q = 0.f;
        for (int j = gi; j < TERMS; j += GRP) {
            const int bb = j / NTPREV, tl = j - bb * NTPREV;
            const int a = (bb * CIN + ci) * NTPREV + tl;
            s += pS[a]; q += pQ[a];
        }
        sredS[gi * CIN + ci] = s;
        sredQ[gi * CIN + ci] = q;
        __syncthreads();
        if (tid < CIN) {
            float ts = 0.f, tq = 0.f;
            #pragma unroll
            for (int g2 = 0; g2 < GRP; g2++) {
                ts += sredS[g2 * CIN + tid];
                tq += sredQ[g2 * CIN + tid];
            }
            const float m = ts * invN;
            const float v = tq * invN - m * m;
            const float sc = gam[tid] * rsqrtf(v + 1e-5f);
            scs[tid] = sc;
            shs[tid] = be[tid] - m * sc;
        }
        __syncthreads();
    }

    for (int i = tid; i < 2 * CIN * 9; i += BLOCK) {
        const int n = i / (CIN * 9), r = i - n * (CIN * 9), ci = r / 9;
        const float wv = w[(co0 + n) * CIN * 9 + r];
        wsm[n][r] = INBN ? wv * scs[ci] : wv;
    }
    if constexpr (INBN) {
        for (int i = tid; i < 2 * CIN; i += BLOCK) {
            const int n = i / CIN, ci = i - n * CIN;
            const float* wp = w + ((co0 + n) * CIN + ci) * 9;
            float s = 0.f;
            #pragma unroll
            for (int k = 0; k < 9; k++) s += wp[k];
            wrow[n][ci] = s;
        }
    }
    __syncthreads();
    if (tid < 2) {
        float c = bias[co0 + tid];
        if constexpr (INBN) {
            for (int ci = 0; ci < CIN; ci++) c = fmaf(wrow[tid][ci], shs[ci], c);
        }
        cadd[tid] = c;
    }
    __syncthreads();

    const int npix = OUTW * OUTW;
    const int pg = blockIdx.x * PIX + p;
    float a0 = 0.f, a1 = 0.f;
    if (pg < npix) {
        const int oh = pg / OUTW, ow = pg - oh * OUTW;
        const float* ib = in + ((size_t)(b * CIN) + cs * CPS) * (INW * INW)
                             + (size_t)(2 * oh) * INW + 2 * ow;
        #pragma unroll 4
        for (int ci = 0; ci < CPS; ci++) {
            const float* ip = ib + (size_t)ci * (INW * INW);
            const int cw = (cs * CPS + ci) * 9;
            #pragma unroll
            for (int kh = 0; kh < 3; kh++) {
                const float* r = ip + kh * INW;
                #pragma unroll
                for (int kw = 0; kw < 3; kw++) {
                    const float xv = r[kw];
                    a0 = fmaf(xv, wsm[0][cw + kh * 3 + kw], a0);
                    a1 = fmaf(xv, wsm[1][cw + kh * 3 + kw], a1);
                }
            }
        }
    }

    float v0 = 0.f, v1 = 0.f;
    if constexpr (CISPLIT > 1) {
        part[cs][p][0] = a0; part[cs][p][1] = a1;
        __syncthreads();
    }
    if (cs == 0) {
        float s0 = a0, s1 = a1;
        if constexpr (CISPLIT > 1) {
            #pragma unroll
            for (int q = 1; q < CISPLIT; q++) { s0 += part[q][p][0]; s1 += part[q][p][1]; }
        }
        if (pg < npix) {
            v0 = fmaxf(s0 + cadd[0], 0.f);
            v1 = fmaxf(s1 + cadd[1], 0.f);
            if constexpr (WRITE) {
                out[(size_t)(b * COUT + co0) * npix + pg] = v0;
                out[(size_t)(b * COUT + co0 + 1) * npix + pg] = v1;
            }
        }
    }

    if constexpr (STATS) {
        if (cs == 0) {
            float sA = v0, qA = v0 * v0, sB = v1, qB = v1 * v1;
            #pragma unroll
            for (int off = 32; off > 0; off >>= 1) {
                sA += __shfl_down(sA, off); qA += __shfl_down(qA, off);
                sB += __shfl_down(sB, off); qB += __shfl_down(qB, off);
            }
            if ((tid & 63) == 0) {
                red[0][0][tid >> 6] = sA; red[0][1][tid >> 6] = qA;
                red[1][0][tid >> 6] = sB; red[1][1][tid >> 6] = qB;
            }
        }
        __syncthreads();
        if (tid == 0) {
            float tsA = 0.f, tqA = 0.f, tsB = 0.f, tqB = 0.f;
            #pragma unroll
            for (int i = 0; i < PIX / 64; i++) {
                tsA += red[0][0][i]; tqA += red[0][1][i];
                tsB += red[1][0][i]; tqB += red[1][1][i];
            }
            pSo[(b * COUT + co0) * NTOUT + blockIdx.x] = tsA;
            pQo[(b * COUT + co0) * NTOUT + blockIdx.x] = tqA;
            pSo[(b * COUT + co0 + 1) * NTOUT + blockIdx.x] = tsB;
            pQo[(b * COUT + co0 + 1) * NTOUT + blockIdx.x] = tqB;
        }
    }
}

// ---------------------------------------------------------------------------
// conv5 (64->128, 15->7, BN4 folded, ci-split 4, stats only) fused with the
// fc/spline tail via a LAST-BLOCK FINALE: each of the 512 blocks publishes
// its per-(b,co) stats, fences, bumps a counter; the block that sees
// old==511 acquires and runs BN5 -> mean -> fc1 -> fc2 -> Thomas -> splines.
// Counter is zeroed by resize_k block 0 every call (stream-ordered earlier).
// Grid: 512 blocks x 256 threads (PIX=64, CISPLIT=4).
// ---------------------------------------------------------------------------
__global__ __launch_bounds__(256) void conv5fc_k(
    const float* __restrict__ in, const float* __restrict__ w,
    const float* __restrict__ bias,
    const float* __restrict__ gam, const float* __restrict__ be,
    const float* __restrict__ pS, const float* __restrict__ pQ,
    float* __restrict__ pS5, float* __restrict__ pQ5,
    const float* __restrict__ g5, const float* __restrict__ be5,
    const float* __restrict__ fc1w, const float* __restrict__ fc1b,
    const float* __restrict__ fc2w, const float* __restrict__ fc2b,
    float* __restrict__ coeff_out, float* __restrict__ splines_out,
    unsigned* __restrict__ ctr)
{
    constexpr int CIN = 64, COUT = 128, INW = 15, OUTW = 7;
    constexpr int CISPLIT = 4, PIX = 64, BLOCK = 256;
    constexpr int CPS = CIN / CISPLIT;
    constexpr int COG = COUT / 2;
    const float invN = 1.0f / 1800.0f;

    __shared__ float wsm[2][CIN * 9];
    __shared__ float scs[CIN], shs[CIN];
    __shared__ float wrow[2][CIN];
    __shared__ float cadd[2];
    __shared__ float part[CISPLIT][PIX][2];
    __shared__ float sredS[BLOCK], sredQ[BLOCK];
    __shared__ unsigned lastFlag;
    // fc tail scratch
    __shared__ float fsc5[128], fsh5[128];
    __shared__ float fch[1024], fh1[1024];
    __shared__ float fysn[240];
    __shared__ float fcoef[24][36];

    const int tid = threadIdx.x;
    const int p   = tid & (PIX - 1);
    const int cs  = tid / PIX;
    const int bc  = blockIdx.x;          // 0..511
    const int b   = bc / COG;
    const int co0 = (bc % COG) * 2;

    // BN4 from conv4 partials (NTPREV=1)
    {
        constexpr int GRP = BLOCK / CIN;   // 4
        const int ci = tid % CIN;
        const int gi = tid / CIN;
        float s = 0.f, q = 0.f;
        for (int j = gi; j < 8; j += GRP) {
            const int a = j * CIN + ci;
            s += pS[a]; q += pQ[a];
        }
        sredS[gi * CIN + ci] = s;
        sredQ[gi * CIN + ci] = q;
        __syncthreads();
        if (tid < CIN) {
            float ts = 0.f, tq = 0.f;
            #pragma unroll
            for (int g2 = 0; g2 < GRP; g2++) {
                ts += sredS[g2 * CIN + tid];
                tq += sredQ[g2 * CIN + tid];
            }
            const float m = ts * invN;
            const float v = tq * invN - m * m;
            const float sc = gam[tid] * rsqrtf(v + 1e-5f);
            scs[tid] = sc;
            shs[tid] = be[tid] - m * sc;
        }
        __syncthreads();
    }

    for (int i = tid; i < 2 * CIN * 9; i += BLOCK) {
        const int n = i / (CIN * 9), r = i - n * (CIN * 9), ci = r / 9;
        wsm[n][r] = w[(co0 + n) * CIN * 9 + r] * scs[ci];
    }
    for (int i = tid; i < 2 * CIN; i += BLOCK) {
        const int n = i / CIN, ci = i - n * CIN;
        const float* wp = w + ((co0 + n) * CIN + ci) * 9;
        float s = 0.f;
        #pragma unroll
        for (int k = 0; k < 9; k++) s += wp[k];
        wrow[n][ci] = s;
    }
    __syncthreads();
    if (tid < 2) {
        float c = bias[co0 + tid];
        for (int ci = 0; ci < CIN; ci++) c = fmaf(wrow[tid][ci], shs[ci], c);
        cadd[tid] = c;
    }
    __syncthreads();

    float a0 = 0.f, a1 = 0.f;
    if (p < 49) {
        const int oh = p / OUTW, ow = p - oh * OUTW;
        const float* ib = in + ((size_t)(b * CIN) + cs * CPS) * (INW * INW)
                             + (size_t)(2 * oh) * INW + 2 * ow;
        #pragma unroll 4
        for (int ci = 0; ci < CPS; ci++) {
            const float* ip = ib + (size_t)ci * (INW * INW);
            const int cw = (cs * CPS + ci) * 9;
            #pragma unroll
            for (int kh = 0; kh < 3; kh++) {
                const float* r = ip + kh * INW;
                #pragma unroll
                for (int kw = 0; kw < 3; kw++) {
                    const float xv = r[kw];
                    a0 = fmaf(xv, wsm[0][cw + kh * 3 + kw], a0);
                    a1 = fmaf(xv, wsm[1][cw + kh * 3 + kw], a1);
                }
            }
        }
    }

    part[cs][p][0] = a0; part[cs][p][1] = a1;
    __syncthreads();
    if (cs == 0) {
        float s0 = a0 + part[1][p][0] + part[2][p][0] + part[3][p][0];
        float s1 = a1 + part[1][p][1] + part[2][p][1] + part[3][p][1];
        float v0 = 0.f, v1 = 0.f;
        if (p < 49) {
            v0 = fmaxf(s0 + cadd[0], 0.f);
            v1 = fmaxf(s1 + cadd[1], 0.f);
        }
        float sA = v0, qA = v0 * v0, sB = v1, qB = v1 * v1;
        #pragma unroll
        for (int off = 32; off > 0; off >>= 1) {
            sA += __shfl_down(sA, off); qA += __shfl_down(qA, off);
            sB += __shfl_down(sB, off); qB += __shfl_down(qB, off);
        }
        if (p == 0) {
            pS5[b * COUT + co0] = sA;
            pQ5[b * COUT + co0] = qA;
            pS5[b * COUT + co0 + 1] = sB;
            pQ5[b * COUT + co0 + 1] = qB;
        }
    }
    __syncthreads();

    // ---- last-block finale ----
    if (tid == 0) {
        __threadfence();   // publish this block's pS5/pQ5 stores
        unsigned old = atomicAdd(ctr, 1u);
        lastFlag = (old == 511u) ? 1u : 0u;
    }
    __syncthreads();
    if (lastFlag == 0u) return;
    __threadfence();       // acquire: all 512 blocks' partials now visible

    const int t = tid;
    if (t < 128) {
        float sv = 0.f, qv = 0.f;
        #pragma unroll
        for (int bb = 0; bb < 8; bb++) { sv += pS5[bb * 128 + t]; qv += pQ5[bb * 128 + t]; }
        float m = sv * (1.f / 392.f);
        float v = qv * (1.f / 392.f) - m * m;
        float sc = g5[t] * rsqrtf(v + 1e-5f);
        fsc5[t] = sc;
        fsh5[t] = be5[t] - m * sc;
    }
    __syncthreads();

    for (int i = t; i < 1024; i += 256) {
        int c = i & 127;
        fch[i] = fmaf(fsc5[c], pS5[i] * (1.f / 49.f), fsh5[c]);
    }
    __syncthreads();

    for (int i = t; i < 1024; i += 256) {
        int bb = i >> 7, j = i & 127;
        float acc = fc1b[j];
        for (int c = 0; c < 128; c++)
            acc = fmaf(fch[(bb << 7) + c], fc1w[(j << 7) + c], acc);
        fh1[i] = fmaxf(acc, 0.f);
    }
    __syncthreads();

    if (t < 240) {
        int bb = t / 30, k = t % 30;
        float acc = fc2b[k];
        for (int j = 0; j < 128; j++)
            acc = fmaf(fh1[(bb << 7) + j], fc2w[(k << 7) + j], acc);
        fysn[t] = acc + (float)(k % 10) * STEP_F;
    }
    __syncthreads();

    if (t < 24) {
        float y[10];
        #pragma unroll
        for (int i = 0; i < 10; i++) y[i] = fysn[t * 10 + i];
        float rhs[9], cp[9], dp[9];
        #pragma unroll
        for (int i = 1; i <= 8; i++)
            rhs[i] = 486.f * (y[i - 1] - 2.f * y[i] + y[i + 1]);
        cp[1] = 0.25f; dp[1] = rhs[1] * 0.25f;
        #pragma unroll
        for (int i = 2; i <= 8; i++) {
            float m = 1.f / (4.f - cp[i - 1]);
            cp[i] = m;
            dp[i] = (rhs[i] - dp[i - 1]) * m;
        }
        float M[10];
        M[0] = 0.f; M[9] = 0.f;
        M[8] = dp[8];
        #pragma unroll
        for (int i = 7; i >= 1; i--) M[i] = dp[i] - cp[i] * M[i + 1];
        #pragma unroll
        for (int i = 0; i < 9; i++) {
            float a = (M[i + 1] - M[i]) * 1.5f;
            float bb2 = M[i] * 0.5f;
            float cc = (y[i + 1] - y[i]) * 9.f - (M[i + 1] + 2.f * M[i]) * (STEP_F / 6.f);
            float dd = y[i];
            fcoef[t][i] = a; fcoef[t][9 + i] = bb2; fcoef[t][18 + i] = cc; fcoef[t][27 + i] = dd;
            coeff_out[t * 36 + i] = a;
            coeff_out[t * 36 + 9 + i] = bb2;
            coeff_out[t * 36 + 18 + i] = cc;
            coeff_out[t * 36 + 27 + i] = dd;
        }
    }
    __syncthreads();

    for (int i = t; i < 24 * 255; i += 256) {
        int bc2 = i / 255, k = i - bc2 * 255;
        float xv = (float)k * (1.0f / 255.0f);
        float xi = floorf(xv * 9.0f);
        xi = fminf(fmaxf(xi, 0.f), 8.f);
        int ix = (int)xi;
        float xf = xv - xi * STEP_F;
        const float* cf = fcoef[bc2];
        splines_out[i] = fmaf(fmaf(fmaf(cf[ix], xf, cf[9 + ix]), xf, cf[18 + ix]), xf, cf[27 + ix]);
    }
}

// ---------------------------------------------------------------------------
// Apply spline to full-res x. One block = 1024 consecutive floats.
// ---------------------------------------------------------------------------
__global__ __launch_bounds__(256) void apply_k(const float* __restrict__ x,
                                               const float* __restrict__ coeff,
                                               float* __restrict__ out)
{
    __shared__ float cf[36];
    const int blk = blockIdx.x;
    const int plane = blk >> 10;
    const int t = threadIdx.x;
    if (t < 36) cf[t] = coeff[plane * 36 + t];
    __syncthreads();

    size_t base = (size_t)blk * 1024 + (size_t)t * 4;
    float4 v = *(const float4*)(x + base);
    f32x4 o;
    #pragma unroll
    for (int k = 0; k < 4; k++) {
        float xv = (k == 0) ? v.x : (k == 1) ? v.y : (k == 2) ? v.z : v.w;
        float xi = floorf(xv * 9.0f);
        xi = fminf(fmaxf(xi, 0.f), 8.f);
        int ix = (int)xi;
        float xf = xv - xi * STEP_F;
        o[k] = fmaf(fmaf(fmaf(cf[ix], xf, cf[9 + ix]), xf, cf[18 + ix]), xf, cf[27 + ix]);
    }
    __builtin_nontemporal_store(o, (f32x4*)(out + base));
}

// ---------------------------------------------------------------------------
extern "C" void kernel_launch(void* const* d_in, const int* in_sizes, int n_in,
                              void* d_out, int out_size, void* d_ws, size_t ws_size,
                              hipStream_t stream) {
    (void)in_sizes; (void)n_in; (void)out_size; (void)ws_size;

    const float* x    = (const float*)d_in[0];
    const float* w1   = (const float*)d_in[1];
    const float* b1   = (const float*)d_in[2];
    const float* w2   = (const float*)d_in[3];
    const float* b2   = (const float*)d_in[4];
    const float* g2   = (const float*)d_in[5];
    const float* be2  = (const float*)d_in[6];
    const float* w3   = (const float*)d_in[7];
    const float* b3   = (const float*)d_in[8];
    const float* g3   = (const float*)d_in[9];
    const float* be3  = (const float*)d_in[10];
    const float* w4   = (const float*)d_in[11];
    const float* b4   = (const float*)d_in[12];
    const float* g4   = (const float*)d_in[13];
    const float* be4  = (const float*)d_in[14];
    const float* w5   = (const float*)d_in[15];
    const float* b5   = (const float*)d_in[16];
    const float* g5   = (const float*)d_in[17];
    const float* be5  = (const float*)d_in[18];
    const float* fc1w = (const float*)d_in[19];
    const float* fc1b = (const float*)d_in[20];
    const float* fc2w = (const float*)d_in[21];
    const float* fc2b = (const float*)d_in[22];

    float* out = (float*)d_out;
    float* wsf = (float*)d_ws;

    // ws: per-block partials (fully overwritten every call; no atomics except
    // the conv5 finale counter, zeroed by resize_k block 0 each call)
    float* pS2 = wsf + 0;      // [8*16*16] = 2048
    float* pQ2 = wsf + 2048;
    float* pS3 = wsf + 4096;   // [8*32*4]  = 1024
    float* pQ3 = wsf + 5120;
    float* pS4 = wsf + 6144;   // [8*64*1]  = 512
    float* pQ4 = wsf + 6656;
    float* pS5 = wsf + 7168;   // [8*128]   = 1024  (spatial sums for fc)
    float* pQ5 = wsf + 8192;
    float* coeff = wsf + 9216; // [24*36]
    unsigned* ctr = (unsigned*)(wsf + 10240);

    // big intermediates in d_out (overwritten by apply_k)
    float* sm  = out;                  // 24*256*256  = 1572864
    float* h1  = out + 1572864;        // 8*8*127*127 = 1032256
    float* h2  = out + 2605120;        // 8*16*63*63  =  508032
    float* h3  = out + 3113152;        // 8*32*31*31  =  246016
    float* h4  = out + 3359168;        // 8*64*15*15  =  115200

    resize_k<<<1536, 256, 0, stream>>>(x, sm, ctr);

    // conv1: 3->8, 256->127
    conv_k<3, 8, 256, 127, 1, 256, 1, 1, false, false, true>
        <<<dim3(64, 32), 256, 0, stream>>>(sm, w1, b1, nullptr, nullptr,
                                           nullptr, nullptr, 0.f,
                                           h1, nullptr, nullptr);
    // conv2: 8->16, 127->63  (writes 16-tile partials)
    conv_k<8, 16, 127, 63, 1, 256, 1, 16, false, true, true>
        <<<dim3(16, 64), 256, 0, stream>>>(h1, w2, b2, nullptr, nullptr,
                                           nullptr, nullptr, 0.f,
                                           h2, pS2, pQ2);
    // conv3: 16->32, 63->31  (BN2 from pS2/pQ2; writes 4-tile partials)
    conv_k<16, 32, 63, 31, 1, 256, 16, 4, true, true, true>
        <<<dim3(4, 128), 256, 0, stream>>>(h2, w3, b3, g2, be2,
                                           pS2, pQ2, 1.0f / 31752.0f,
                                           h3, pS3, pQ3);
    // conv4: 32->64, 31->15  (BN3; ci-split 2; 1-tile partials)
    conv_k<32, 64, 31, 15, 2, 256, 4, 1, true, true, true>
        <<<dim3(1, 256), 512, 0, stream>>>(h3, w4, b4, g3, be3,
                                           pS3, pQ3, 1.0f / 7688.0f,
                                           h4, pS4, pQ4);
    // conv5 + fc/spline tail (last-block finale)
    conv5fc_k<<<512, 256, 0, stream>>>(h4, w5, b5, g4, be4,
                                       pS4, pQ4, pS5, pQ5,
                                       g5, be5, fc1w, fc1b, fc2w, fc2b,
                                       coeff, out + SPLINE_OFF, ctr);

    apply_k<<<24576, 256, 0, stream>>>(x, coeff, out);
}